// Round 2
// baseline (106.881 us; speedup 1.0000x reference)
//
#include <hip/hip_runtime.h>

#define NB 8
#define IN_HW 512
#define OHW 128
#define VOLD 128

// Gaussian splat weights
#define E1f 0.60653065971263342f   // exp(-0.5)
#define E2f 0.13533528323661270f   // exp(-2.0)

// LDS column stride: 132 floats = 528 B -> every column 16B-aligned,
// word bank = (4*w + d) % 32 -> float4 reads across lanes measured 0 conflicts.
#define CSTR 132

// ---------------------------------------------------------------------------
// Fused kernel: one block of 512 threads per (b, h) output row-slab.
//
// Phase A (t < 384, r = t>>7 in {0,1,2}, wc = t&127): recompute the resized
//   pixel (hr = h+r-1, wc) of both images directly from the 512x512 inputs
//   (antialiased bilinear, taps 4i-2..4i+5, raw weights {1,3,5,7,7,5,3,1}/8,
//   renormalized). 3x redundant across blocks but resize is cheap and the
//   inputs are L2-resident. Depth path fp64 (feeds trunc -> d_idx), x-ray fp32.
//   Taps come from the three ALIGNED float4 blocks j-1, j, j+1 (clamped);
//   out-of-image taps are zeroed through the tap VALUES with the weight
//   constants kept exact -> bit-identical to the weight-zero formulation.
// Phase B: zero LDS col[130][CSTR]; barrier.
// Phase C: scatter the 7-tap depth-pooled profile
//   q(d) = x * sum_{t=d-1..d+1, 0<=t<=127} w(t - d_idx)
//   into col[wc+1][d] via LDS atomicAdd (ds_add_f32; 3 rows share a column
//   from different waves). Summation-order change vs serial RMW is ~1 ulp,
//   far under the 6.4e-3 tolerance. barrier.
// Phase D: all 512 threads gather 3 w-neighbors (float4 LDS reads) and write
//   32 depth-slices each, coalesced along w. 16 waves/CU during the store
//   stream (vs 8 in the split version).
// ---------------------------------------------------------------------------
__global__ __launch_bounds__(512, 2) void fused_kernel(
    const float* __restrict__ depth, const float* __restrict__ xray,
    float* __restrict__ out)
{
    __shared__ __align__(16) float col[130][CSTR];  // 68,640 B -> 2 blocks/CU

    int t   = threadIdx.x;
    int blk = blockIdx.x;
    int h = blk & (OHW - 1);
    int b = blk >> 7;

    int wc = t & (OHW - 1);
    int r  = t >> 7;            // 0..3 ; r==3 idle in phases A/C
    int hr = h + r - 1;

    // ---- Phase A: resize (register-only result: accXf, di) ----
    float accXf = 0.f;
    int   di    = -1000;        // sentinel: nothing to scatter

    if (r < 3 && hr >= 0 && hr < OHW) {
        int r0 = 4 * hr - 2, c0 = 4 * wc - 2;
        // row/col raw-weight sums are exact: 4.0 interior, 3.5 at the edges
        double sr = (hr == 0 || hr == OHW - 1) ? 3.5 : 4.0;
        double sc = (wc == 0 || wc == OHW - 1) ? 3.5 : 4.0;
        double invd = 1.0 / (sr * sc);
        float  invf = (float)invd;

        int f0 = wc - 1; if (f0 < 0) f0 = 0;
        int f2 = wc + 1; if (f2 > (IN_HW / 4) - 1) f2 = (IN_HW / 4) - 1;
        int f1 = wc;

        const float4* dbase = (const float4*)(depth + (size_t)b * IN_HW * IN_HW);
        const float4* xbase = (const float4*)(xray  + (size_t)b * IN_HW * IN_HW);

        bool ledge = (wc == 0);            // taps l=0,1 out of image
        bool redge = (wc == OHW - 1);      // taps l=6,7 out of image

        double accD = 0.0;
        float  accX = 0.f;
#pragma unroll
        for (int k = 0; k < 8; ++k) {
            int rr = r0 + k;
            if (rr < 0 || rr >= IN_HW) continue;       // wave-uniform (hr uniform)
            const float4* drow = dbase + (size_t)rr * (IN_HW / 4);
            const float4* xrow = xbase + (size_t)rr * (IN_HW / 4);
            float4 d0 = drow[f0], d1 = drow[f1], d2 = drow[f2];
            float4 x0 = xrow[f0], x1 = xrow[f1], x2 = xrow[f2];
            // taps l=0..7 -> floats 4wc-2..4wc+5 = {d0.z,d0.w, d1.xyzw, d2.x,d2.y}
            float dt[8] = {d0.z, d0.w, d1.x, d1.y, d1.z, d1.w, d2.x, d2.y};
            float xt[8] = {x0.z, x0.w, x1.x, x1.y, x1.z, x1.w, x2.x, x2.y};
            if (ledge) { dt[0] = dt[1] = 0.f; xt[0] = xt[1] = 0.f; }
            if (redge) { dt[6] = dt[7] = 0.f; xt[6] = xt[7] = 0.f; }
            // exact binary-fraction weights; zeroed taps contribute exactly +0.0
            double rd = 0.125 * (double)dt[0] + 0.375 * (double)dt[1]
                      + 0.625 * (double)dt[2] + 0.875 * (double)dt[3]
                      + 0.875 * (double)dt[4] + 0.625 * (double)dt[5]
                      + 0.375 * (double)dt[6] + 0.125 * (double)dt[7];
            float  rx = 0.125f * xt[0] + 0.375f * xt[1]
                      + 0.625f * xt[2] + 0.875f * xt[3]
                      + 0.875f * xt[4] + 0.625f * xt[5]
                      + 0.375f * xt[6] + 0.125f * xt[7];
            const double rawk[8] = {0.125, 0.375, 0.625, 0.875,
                                    0.875, 0.625, 0.375, 0.125};
            accD += rawk[k] * rd;
            accX += (float)rawk[k] * rx;
        }
        accD *= invd;
        accX *= invf;

        // nd = depth_r / 100 ; d_idx = trunc(nd * 127), clipped to [0,127]
        double nd = accD * (1.0 / 100.0);
        int dii = (int)(nd * 127.0);
        di = min(max(dii, 0), VOLD - 1);
        accXf = accX;
    }

    // ---- Phase B: zero col (flat float4; 130*132/4 = 4290 float4) ----
    {
        float4* colv = (float4*)&col[0][0];
        for (int k = t; k < (130 * CSTR) / 4; k += 512)
            colv[k] = float4{0.f, 0.f, 0.f, 0.f};
    }
    __syncthreads();

    // ---- Phase C: scatter via LDS atomic add ----
    if (di >= 0) {
        // S[o+3] = w(o-1)+w(o)+w(o+1), o = d - d_idx in [-3,3]
        // A: d==0 edge (t=-1 dropped) ; Z: d==127 edge (t=128 dropped)
        const float S[7] = {E2f, E2f + E1f, E2f + E1f + 1.f, 1.f + 2.f * E1f,
                            1.f + E1f + E2f, E1f + E2f, E2f};
        const float A[7] = {E2f, E2f + E1f, E1f + 1.f, 1.f + E1f,
                            E1f + E2f, E2f, 0.f};
        const float Z[7] = {0.f, E2f, E2f + E1f, 1.f + E1f,
                            1.f + E1f, E1f + E2f, E2f};
        float* c = &col[wc + 1][0];
#pragma unroll
        for (int o = -3; o <= 3; ++o) {
            int d = di + o;
            if (d < 0 || d > VOLD - 1) continue;
            float w = S[o + 3];
            if (d == 0)            w = A[o + 3];
            else if (d == VOLD-1)  w = Z[o + 3];
            atomicAdd(&c[d], accXf * w);
        }
    }
    __syncthreads();

    // ---- Phase D: gather 3 w-neighbors, 32 depths per thread, store ----
    int q4 = t >> 7;                              // depth quarter 0..3
    const float inv27 = 1.f / 27.f;
    const float4* colv = (const float4*)&col[0][0];
    int base = wc * (CSTR / 4) + q4 * 8;          // float4 idx of col[wc][q4*32]
    float* obase = out + ((size_t)(b * VOLD + q4 * 32) * OHW + h) * OHW + wc;
#pragma unroll
    for (int q = 0; q < 8; ++q) {
        float4 a  = colv[base + q];
        float4 c1 = colv[base + q + (CSTR / 4)];
        float4 c2 = colv[base + q + 2 * (CSTR / 4)];
        float4 v;
        v.x = (a.x + c1.x + c2.x) * inv27;
        v.y = (a.y + c1.y + c2.y) * inv27;
        v.z = (a.z + c1.z + c2.z) * inv27;
        v.w = (a.w + c1.w + c2.w) * inv27;
        float* o = obase + (size_t)(q * 4) * OHW * OHW;
        o[0 * OHW * OHW] = v.x;
        o[1 * OHW * OHW] = v.y;
        o[2 * OHW * OHW] = v.z;
        o[3 * OHW * OHW] = v.w;
    }
}

extern "C" void kernel_launch(void* const* d_in, const int* in_sizes, int n_in,
                              void* d_out, int out_size, void* d_ws, size_t ws_size,
                              hipStream_t stream)
{
    const float* depth = (const float*)d_in[0];
    const float* xray  = (const float*)d_in[1];
    float* out = (float*)d_out;
    (void)d_ws; (void)ws_size;

    fused_kernel<<<NB * OHW, 512, 0, stream>>>(depth, xray, out);
}

// Round 3
// 101.680 us; speedup vs baseline: 1.0512x; 1.0512x over previous
//
#include <hip/hip_runtime.h>

#define NB 8
#define IN_HW 512
#define OHW 128
#define VOLD 128

// Gaussian splat weights
#define E1f 0.60653065971263342f   // exp(-0.5)
#define E2f 0.13533528323661270f   // exp(-2.0)

// LDS column stride: 132 floats = 528 B -> every column 16B-aligned,
// word bank = (4*w + d) % 32 -> float4 reads across lanes measured 0 conflicts.
#define CSTR 132

// ---------------------------------------------------------------------------
// Kernel 1 (unchanged from round 1, verified): antialiased bilinear resize
// 512x512 -> 128x128. Depth path fp64 (feeds truncation), x-ray path fp32.
// Taps c = 4j-2..4j+5 come from the three ALIGNED float4 blocks at float4
// index j-1, j, j+1 (clamped; OOB taps carry weight 0.0 -> exact no-op).
// ---------------------------------------------------------------------------
__global__ __launch_bounds__(256) void resize_kernel(
    const float* __restrict__ depth, const float* __restrict__ xray,
    int* __restrict__ didx, float* __restrict__ xr)
{
    int idx = blockIdx.x * blockDim.x + threadIdx.x;   // 8*128*128 threads
    int j = idx & (OHW - 1);
    int i = (idx >> 7) & (OHW - 1);
    int b = idx >> 14;

    const double rawd[8] = {0.125, 0.375, 0.625, 0.875, 0.875, 0.625, 0.375, 0.125};

    int r0 = 4 * i - 2, c0 = 4 * j - 2;
    double wr[8], wc[8];
    double sr = 0.0, sc = 0.0;
#pragma unroll
    for (int k = 0; k < 8; ++k) {
        int r = r0 + k;
        wr[k] = (r >= 0 && r < IN_HW) ? rawd[k] : 0.0; sr += wr[k];
        int c = c0 + k;
        wc[k] = (c >= 0 && c < IN_HW) ? rawd[k] : 0.0; sc += wc[k];
    }
    double invd = 1.0 / (sr * sc);
    float  invf = (float)invd;

    // float4-index columns, clamped (safe: OOB taps have zero weight)
    int f0 = j - 1; if (f0 < 0) f0 = 0;
    int f2 = j + 1; if (f2 > (IN_HW / 4) - 1) f2 = (IN_HW / 4) - 1;
    int f1 = j;

    const float4* dbase = (const float4*)(depth + (size_t)b * IN_HW * IN_HW);
    const float4* xbase = (const float4*)(xray  + (size_t)b * IN_HW * IN_HW);

    double accD = 0.0;
    float  accX = 0.f;
#pragma unroll
    for (int k = 0; k < 8; ++k) {
        if (wr[k] == 0.0) continue;          // uniform across the wave (i fixed)
        int r = r0 + k;
        const float4* drow = dbase + (size_t)r * (IN_HW / 4);
        const float4* xrow = xbase + (size_t)r * (IN_HW / 4);
        float4 d0 = drow[f0], d1 = drow[f1], d2 = drow[f2];
        float4 x0 = xrow[f0], x1 = xrow[f1], x2 = xrow[f2];
        // taps l=0..7 -> floats 4j-2..4j+5 = {d0.z,d0.w, d1.xyzw, d2.x,d2.y}
        float dt[8] = {d0.z, d0.w, d1.x, d1.y, d1.z, d1.w, d2.x, d2.y};
        float xt[8] = {x0.z, x0.w, x1.x, x1.y, x1.z, x1.w, x2.x, x2.y};
        double rd = 0.0;
        float  rx = 0.f;
#pragma unroll
        for (int l = 0; l < 8; ++l) {
            rd += wc[l] * (double)dt[l];     // wc==0 on OOB taps -> exact no-op
            rx += (float)wc[l] * xt[l];
        }
        accD += wr[k] * rd;
        accX += (float)wr[k] * rx;
    }
    accD *= invd;
    accX *= invf;

    // nd = depth_r / 100 ; d_idx = trunc(nd * 127), clipped to [0,127]
    double nd = accD * (1.0 / 100.0);
    int di = (int)(nd * 127.0);
    di = min(max(di, 0), VOLD - 1);

    didx[idx] = di;
    xr[idx]   = accX;
}

// ---------------------------------------------------------------------------
// Kernel 2: one block of 1024 threads per (b, h). Same LDS (68.6 KB) ->
// 2 blocks/CU -> 32 waves/CU (vs 8 with 256 threads): the 67 MB store
// stream now has max occupancy behind it, and the zero-fill is 4x wider.
//
// Scatter: 390 threads, one (row r, halo col c) pair each, 7-tap profile
//   q(d) = x * sum_{t=d-1..d+1, 0<=t<=127} w(t - d_idx)
// added into col[c][d] via LDS atomicAdd (ds_add_f32; 3 rows share a
// column). Order-of-add change vs serial is ~1 ulp (validated round 2).
// Gather: all 1024 threads; thread t -> (w = t&127, depth block dq = t>>7),
// 16 depths each, float4 LDS reads, coalesced 256 B stores.
// ---------------------------------------------------------------------------
__global__ __launch_bounds__(1024) void splat_pool_kernel(
    const int* __restrict__ didx, const float* __restrict__ xr,
    float* __restrict__ out)
{
    __shared__ __align__(16) float col[130][CSTR];  // 68,640 B

    int t   = threadIdx.x;
    int blk = blockIdx.x;
    int h = blk & (OHW - 1);
    int b = blk >> 7;

    // issue scatter-input loads first (coalesced along c within each row group)
    float xv = 0.f;
    int   dv = 1 << 20;                 // sentinel: all taps out of range
    int   cc = 0;
    if (t < 390) {
        int r = t / 130;                // 0..2
        cc = t - r * 130;               // 0..129 halo column
        int wc = cc - 1;
        int hr = h + r - 1;
        if (hr >= 0 && hr < OHW && wc >= 0 && wc < OHW) {
            int g = (b * OHW + hr) * OHW + wc;
            xv = xr[g];
            dv = didx[g];
        }
    }

    // zero col (flat float4; 130*132/4 = 4290 float4)
    {
        float4* colv = (float4*)&col[0][0];
        for (int k = t; k < (130 * CSTR) / 4; k += 1024)
            colv[k] = float4{0.f, 0.f, 0.f, 0.f};
    }
    __syncthreads();

    // scatter via LDS atomic add (sentinel dv makes every d out of range)
    if (t < 390) {
        // S[o+3] = w(o-1)+w(o)+w(o+1), o = d - d_idx in [-3,3]
        // A: d==0 edge (t=-1 dropped) ; Z: d==127 edge (t=128 dropped)
        const float S[7] = {E2f, E2f + E1f, E2f + E1f + 1.f, 1.f + 2.f * E1f,
                            1.f + E1f + E2f, E1f + E2f, E2f};
        const float A[7] = {E2f, E2f + E1f, E1f + 1.f, 1.f + E1f,
                            E1f + E2f, E2f, 0.f};
        const float Z[7] = {0.f, E2f, E2f + E1f, 1.f + E1f,
                            1.f + E1f, E1f + E2f, E2f};
        float* c = &col[cc][0];
#pragma unroll
        for (int o = -3; o <= 3; ++o) {
            int d = dv + o;
            if (d < 0 || d > VOLD - 1) continue;
            float w = S[o + 3];
            if (d == 0)            w = A[o + 3];
            else if (d == VOLD-1)  w = Z[o + 3];
            atomicAdd(&c[d], xv * w);
        }
    }
    __syncthreads();

    // gather 3 w-neighbors with float4 LDS reads; 16 depths per thread
    int w  = t & (OHW - 1);
    int dq = t >> 7;                              // depth block 0..7
    const float inv27 = 1.f / 27.f;
    const float4* colv = (const float4*)&col[0][0];
    int base = w * (CSTR / 4) + dq * 4;           // float4 idx of col[w][dq*16]
    float* obase = out + ((size_t)(b * VOLD + dq * 16) * OHW + h) * OHW + w;
#pragma unroll
    for (int q = 0; q < 4; ++q) {
        float4 a  = colv[base + q];
        float4 c1 = colv[base + q + (CSTR / 4)];
        float4 c2 = colv[base + q + 2 * (CSTR / 4)];
        float4 v;
        v.x = (a.x + c1.x + c2.x) * inv27;
        v.y = (a.y + c1.y + c2.y) * inv27;
        v.z = (a.z + c1.z + c2.z) * inv27;
        v.w = (a.w + c1.w + c2.w) * inv27;
        float* o = obase + (size_t)(q * 4) * OHW * OHW;
        o[0 * OHW * OHW] = v.x;
        o[1 * OHW * OHW] = v.y;
        o[2 * OHW * OHW] = v.z;
        o[3 * OHW * OHW] = v.w;
    }
}

extern "C" void kernel_launch(void* const* d_in, const int* in_sizes, int n_in,
                              void* d_out, int out_size, void* d_ws, size_t ws_size,
                              hipStream_t stream)
{
    const float* depth = (const float*)d_in[0];
    const float* xray  = (const float*)d_in[1];
    float* out = (float*)d_out;

    const int NPIX = NB * OHW * OHW;           // 131072
    int*   didx = (int*)d_ws;
    float* xrs  = (float*)((char*)d_ws + (size_t)NPIX * sizeof(int));

    resize_kernel<<<NPIX / 256, 256, 0, stream>>>(depth, xray, didx, xrs);
    splat_pool_kernel<<<NB * OHW, 1024, 0, stream>>>(didx, xrs, out);
}